// Round 1
// baseline (5499.165 us; speedup 1.0000x reference)
//
#include <hip/hip_runtime.h>
#include <hip/hip_bf16.h>
#include <stdint.h>

#define T_STEPS 256
#define BATCH   16
#define HIDDIM  1024
#define VOCAB   32000
#define TB      4096   // T_STEPS * BATCH

typedef __attribute__((ext_vector_type(8))) short  short8;
typedef __attribute__((ext_vector_type(4))) float  floatx4;

__device__ inline unsigned short f2bfu(float x) {
  __hip_bfloat16 h = __float2bfloat16(x);
  unsigned short u;
  __builtin_memcpy(&u, &h, 2);
  return u;
}
__device__ inline float bfu2f(unsigned short u) {
  __hip_bfloat16 h;
  __builtin_memcpy(&h, &u, 2);
  return __bfloat162float(h);
}

// ---------------- transpose + convert: src fp32 [K][N] -> dst bf16 [N][K] (+optional lo residual)
__global__ __launch_bounds__(256) void transpose_cvt(
    const float* __restrict__ src, unsigned short* __restrict__ dst,
    unsigned short* __restrict__ dst_lo, int K, int N) {
  __shared__ float tile[64][65];
  int n0 = blockIdx.x * 64, k0 = blockIdx.y * 64;
  int tid = threadIdx.x;
#pragma unroll
  for (int j = 0; j < 16; ++j) {
    int idx = j * 256 + tid;
    int kl = idx >> 6, nl = idx & 63;
    tile[kl][nl] = src[(size_t)(k0 + kl) * N + n0 + nl];
  }
  __syncthreads();
#pragma unroll
  for (int j = 0; j < 16; ++j) {
    int idx = j * 256 + tid;
    int nl = idx >> 6, kl = idx & 63;   // kl fast-varying -> coalesced writes along K
    float v = tile[kl][nl];
    unsigned short hi = f2bfu(v);
    dst[(size_t)(n0 + nl) * K + k0 + kl] = hi;
    if (dst_lo) dst_lo[(size_t)(n0 + nl) * K + k0 + kl] = f2bfu(v - bfu2f(hi));
  }
}

// ---------------- embedding gather + bf16 convert
__global__ __launch_bounds__(256) void gather_cvt(
    const int* __restrict__ X, const float* __restrict__ We,
    unsigned short* __restrict__ emb) {
  int r = blockIdx.x;                 // 0..4095 = t*16+b
  int row = X[r];
  int c = threadIdx.x * 4;
  float4 v = *(const float4*)(We + (size_t)row * HIDDIM + c);
  ushort4 o;
  o.x = f2bfu(v.x); o.y = f2bfu(v.y); o.z = f2bfu(v.z); o.w = f2bfu(v.w);
  *(ushort4*)(emb + (size_t)r * HIDDIM + c) = o;
}

// ---------------- bf16 MFMA GEMM: C[M][N] = A[M][K] @ BT[N][K]^T + bias, m97-style
#define BM 128
#define BN 128
#define BK 64

__device__ inline void glds16(const unsigned short* gp, unsigned short* lp) {
  // 16B/lane direct global->LDS. LDS dest: wave-uniform base + lane*16 (HW-forced layout).
  __builtin_amdgcn_global_load_lds(
      (__attribute__((address_space(1))) unsigned int*)(uintptr_t)gp,
      (__attribute__((address_space(3))) unsigned int*)(unsigned int)(uintptr_t)lp,
      16, 0, 0);
}

__global__ __launch_bounds__(256) void gemm_bf16(
    const unsigned short* __restrict__ A,   // [M][K] bf16, K contiguous
    const unsigned short* __restrict__ BT,  // [N][K] bf16, K contiguous
    const float* __restrict__ bias,         // [N]
    float* __restrict__ C,                  // [M][N] fp32
    int N, int K) {
  __shared__ unsigned short As[BM * BK];    // [128][64], unpadded (global_load_lds layout)
  __shared__ unsigned short Bs[BN * BK];
  int tid = threadIdx.x;
  int wave = tid >> 6, lane = tid & 63;
  int l15 = lane & 15, quad = lane >> 4;
  int m0 = blockIdx.y * BM, n0 = blockIdx.x * BN;
  int wm = (wave >> 1) * 64, wn = (wave & 1) * 64;
  int lrow = lane >> 3, lk = (lane & 7) * 8;
  floatx4 acc[4][4] = {};
  for (int kt = 0; kt < K; kt += BK) {
    __syncthreads();                        // LDS reuse guard
#pragma unroll
    for (int i = 0; i < 4; ++i) {
      int rb = wave * 32 + i * 8;           // wave-uniform row base (8 rows/instr)
      glds16(A  + (size_t)(m0 + rb + lrow) * K + kt + lk, As + rb * BK);
      glds16(BT + (size_t)(n0 + rb + lrow) * K + kt + lk, Bs + rb * BK);
    }
    __syncthreads();                        // drains vmcnt -> staging complete
#pragma unroll
    for (int ks = 0; ks < 2; ++ks) {
      short8 af[4], bv[4];
#pragma unroll
      for (int i = 0; i < 4; ++i)
        af[i] = *(const short8*)(As + (wm + i * 16 + l15) * BK + ks * 32 + quad * 8);
#pragma unroll
      for (int i = 0; i < 4; ++i)
        bv[i] = *(const short8*)(Bs + (wn + i * 16 + l15) * BK + ks * 32 + quad * 8);
#pragma unroll
      for (int mt = 0; mt < 4; ++mt)
#pragma unroll
        for (int nt = 0; nt < 4; ++nt)
          acc[mt][nt] = __builtin_amdgcn_mfma_f32_16x16x32_bf16(af[mt], bv[nt], acc[mt][nt], 0, 0, 0);
    }
  }
  // epilogue: C[m][n], row=quad*4+reg, col=lane&15 (m89-verified layout)
#pragma unroll
  for (int nt = 0; nt < 4; ++nt) {
    int gn = n0 + wn + nt * 16 + l15;
    float bvv = bias ? bias[gn] : 0.0f;
#pragma unroll
    for (int mt = 0; mt < 4; ++mt) {
      int gm = m0 + wm + mt * 16 + quad * 4;
#pragma unroll
      for (int r = 0; r < 4; ++r)
        C[(size_t)(gm + r) * N + gn] = acc[mt][nt][r] + bvv;
    }
  }
}

// ---------------- sequential scan: h_t = tanh(pre_t + h_{t-1} @ W_hh)
// 64 single-wave WGs, each owns 16 output cols; W_hh^T slice persistent in VGPRs as bf16 hi/lo.
// 3-term hi/lo MFMA gives effective-fp32 accuracy. Device-scope atomic barrier per step.
#define SCAN_WGS 64
__global__ __launch_bounds__(64) void scan_kernel(
    const float* __restrict__ pre,            // [TB][HIDDIM], b_h already folded in
    const unsigned short* __restrict__ WThi,  // [m=1024][k=1024]  W_hh[k][m] hi
    const unsigned short* __restrict__ WTlo,
    unsigned short* __restrict__ h_hi,        // [TB][HIDDIM] hidden states (bf16 hi)
    unsigned short* __restrict__ h_lo,
    unsigned int* __restrict__ bar) {
  int lane = threadIdx.x;
  int l15 = lane & 15, quad = lane >> 4;
  int mslice = blockIdx.x * 16;
  short8 Ahi[32], Alo[32];                    // A[m][k]: m=lane&15, k=quad*8+j
  {
    const unsigned short* wh = WThi + (size_t)(mslice + l15) * HIDDIM + quad * 8;
    const unsigned short* wl = WTlo + (size_t)(mslice + l15) * HIDDIM + quad * 8;
#pragma unroll
    for (int kt = 0; kt < 32; ++kt) {
      Ahi[kt] = *(const short8*)(wh + kt * 32);
      Alo[kt] = *(const short8*)(wl + kt * 32);
    }
  }
  for (int t = 0; t < T_STEPS; ++t) {
    floatx4 acc = {0.f, 0.f, 0.f, 0.f};
    if (t > 0) {
      // B[k][n]: n=batch=lane&15, k=quad*8+j  ->  read h_{t-1}[n][k]
      const unsigned short* bh = h_hi + ((size_t)(t - 1) * BATCH + l15) * HIDDIM + quad * 8;
      const unsigned short* bl = h_lo + ((size_t)(t - 1) * BATCH + l15) * HIDDIM + quad * 8;
#pragma unroll
      for (int kt = 0; kt < 32; ++kt) {
        short8 Bh = *(const short8*)(bh + kt * 32);
        short8 Bl = *(const short8*)(bl + kt * 32);
        acc = __builtin_amdgcn_mfma_f32_16x16x32_bf16(Ahi[kt], Bh, acc, 0, 0, 0);
        acc = __builtin_amdgcn_mfma_f32_16x16x32_bf16(Alo[kt], Bh, acc, 0, 0, 0);
        acc = __builtin_amdgcn_mfma_f32_16x16x32_bf16(Ahi[kt], Bl, acc, 0, 0, 0);
      }
    }
    // C[m][n]: this lane holds batch n=l15, cols mslice+quad*4+{0..3}
    size_t orow = ((size_t)t * BATCH + l15) * HIDDIM + mslice + quad * 4;
    float4 p = *(const float4*)(pre + orow);
    ushort4 sh, sl;
    {
      float z, th; unsigned short hb;
      z = acc[0] + p.x; th = tanhf(z); hb = f2bfu(th); sh.x = hb; sl.x = f2bfu(th - bfu2f(hb));
      z = acc[1] + p.y; th = tanhf(z); hb = f2bfu(th); sh.y = hb; sl.y = f2bfu(th - bfu2f(hb));
      z = acc[2] + p.z; th = tanhf(z); hb = f2bfu(th); sh.z = hb; sl.z = f2bfu(th - bfu2f(hb));
      z = acc[3] + p.w; th = tanhf(z); hb = f2bfu(th); sh.w = hb; sl.w = f2bfu(th - bfu2f(hb));
    }
    *(ushort4*)(h_hi + orow) = sh;
    *(ushort4*)(h_lo + orow) = sl;
    // ---- device-scope barrier (release stores -> arrive -> spin -> acquire)
    __threadfence();
    if (lane == 0) {
      atomicAdd(bar, 1u);
      unsigned int target = (unsigned int)SCAN_WGS * (t + 1);
      int guard = 0;
      while (__hip_atomic_load(bar, __ATOMIC_RELAXED, __HIP_MEMORY_SCOPE_AGENT) < target) {
        __builtin_amdgcn_s_sleep(2);
        if (++guard > (1 << 20)) break;   // bounded failsafe; never trips in normal operation
      }
    }
    __threadfence();
  }
}

extern "C" void kernel_launch(void* const* d_in, const int* in_sizes, int n_in,
                              void* d_out, int out_size, void* d_ws, size_t ws_size,
                              hipStream_t stream) {
  const int*   X    = (const int*)d_in[0];
  const float* W_e  = (const float*)d_in[1];
  const float* W_xh = (const float*)d_in[2];
  const float* W_hh = (const float*)d_in[3];
  const float* b_h  = (const float*)d_in[4];
  const float* W_hq = (const float*)d_in[5];
  const float* b_q  = (const float*)d_in[6];
  float* out = (float*)d_out;

  char* w = (char*)d_ws;                                      // total used: ~113.8 MB
  unsigned short* WhqT   = (unsigned short*)(w + 0);          // 65,536,000  [32000][1024]
  unsigned short* WxhT   = (unsigned short*)(w + 65536000);   //  2,097,152  [1024][1024]
  unsigned short* WhhThi = (unsigned short*)(w + 67633152);   //  2,097,152
  unsigned short* WhhTlo = (unsigned short*)(w + 69730304);   //  2,097,152
  unsigned short* emb    = (unsigned short*)(w + 71827456);   //  8,388,608  [4096][1024]
  float*          pre    = (float*)        (w + 80216064);    // 16,777,216  [4096][1024]
  unsigned short* h_hi   = (unsigned short*)(w + 96993280);   //  8,388,608  [4096][1024]
  unsigned short* h_lo   = (unsigned short*)(w + 105381888);  //  8,388,608
  unsigned int*   bar    = (unsigned int*) (w + 113770496);   //  64

  hipMemsetAsync(bar, 0, 64, stream);
  transpose_cvt<<<dim3(VOCAB / 64, HIDDIM / 64), 256, 0, stream>>>(W_hq, WhqT, nullptr, HIDDIM, VOCAB);
  transpose_cvt<<<dim3(HIDDIM / 64, HIDDIM / 64), 256, 0, stream>>>(W_xh, WxhT, nullptr, HIDDIM, HIDDIM);
  transpose_cvt<<<dim3(HIDDIM / 64, HIDDIM / 64), 256, 0, stream>>>(W_hh, WhhThi, WhhTlo, HIDDIM, HIDDIM);
  gather_cvt<<<TB, 256, 0, stream>>>(X, W_e, emb);
  gemm_bf16<<<dim3(HIDDIM / BN, TB / BM), 256, 0, stream>>>(emb, WxhT, b_h, pre, HIDDIM, HIDDIM);
  scan_kernel<<<SCAN_WGS, 64, 0, stream>>>(pre, WhhThi, WhhTlo, h_hi, h_lo, bar);
  gemm_bf16<<<dim3(VOCAB / BN, TB / BM), 256, 0, stream>>>(h_hi, WhqT, b_q, out, VOCAB, HIDDIM);
}

// Round 2
// 4001.526 us; speedup vs baseline: 1.3743x; 1.3743x over previous
//
#include <hip/hip_runtime.h>
#include <hip/hip_bf16.h>
#include <stdint.h>

#define T_STEPS 256
#define BATCH   16
#define HIDDIM  1024
#define VOCAB   32000
#define TB      4096   // T_STEPS * BATCH

typedef __attribute__((ext_vector_type(8))) short  short8;
typedef __attribute__((ext_vector_type(4))) float  floatx4;

__device__ inline unsigned short f2bfu(float x) {
  __hip_bfloat16 h = __float2bfloat16(x);
  unsigned short u;
  __builtin_memcpy(&u, &h, 2);
  return u;
}
__device__ inline float bfu2f(unsigned short u) {
  __hip_bfloat16 h;
  __builtin_memcpy(&h, &u, 2);
  return __bfloat162float(h);
}

// ---------------- transpose + convert: src fp32 [K][N] -> dst bf16 [N][K] (+optional lo residual)
__global__ __launch_bounds__(256) void transpose_cvt(
    const float* __restrict__ src, unsigned short* __restrict__ dst,
    unsigned short* __restrict__ dst_lo, int K, int N) {
  __shared__ float tile[64][65];
  int n0 = blockIdx.x * 64, k0 = blockIdx.y * 64;
  int tid = threadIdx.x;
#pragma unroll
  for (int j = 0; j < 16; ++j) {
    int idx = j * 256 + tid;
    int kl = idx >> 6, nl = idx & 63;
    tile[kl][nl] = src[(size_t)(k0 + kl) * N + n0 + nl];
  }
  __syncthreads();
#pragma unroll
  for (int j = 0; j < 16; ++j) {
    int idx = j * 256 + tid;
    int nl = idx >> 6, kl = idx & 63;   // kl fast-varying -> coalesced writes along K
    float v = tile[kl][nl];
    unsigned short hi = f2bfu(v);
    dst[(size_t)(n0 + nl) * K + k0 + kl] = hi;
    if (dst_lo) dst_lo[(size_t)(n0 + nl) * K + k0 + kl] = f2bfu(v - bfu2f(hi));
  }
}

// ---------------- embedding gather + bf16 convert
__global__ __launch_bounds__(256) void gather_cvt(
    const int* __restrict__ X, const float* __restrict__ We,
    unsigned short* __restrict__ emb) {
  int r = blockIdx.x;                 // 0..4095 = t*16+b
  int row = X[r];
  int c = threadIdx.x * 4;
  float4 v = *(const float4*)(We + (size_t)row * HIDDIM + c);
  ushort4 o;
  o.x = f2bfu(v.x); o.y = f2bfu(v.y); o.z = f2bfu(v.z); o.w = f2bfu(v.w);
  *(ushort4*)(emb + (size_t)r * HIDDIM + c) = o;
}

// ---------------- bf16 MFMA GEMM: C[M][N] = A[M][K] @ BT[N][K]^T + bias, m97-style
#define BM 128
#define BN 128
#define BK 64

__device__ inline void glds16(const unsigned short* gp, unsigned short* lp) {
  // 16B/lane direct global->LDS. LDS dest: wave-uniform base + lane*16 (HW-forced layout).
  __builtin_amdgcn_global_load_lds(
      (__attribute__((address_space(1))) unsigned int*)(uintptr_t)gp,
      (__attribute__((address_space(3))) unsigned int*)(unsigned int)(uintptr_t)lp,
      16, 0, 0);
}

__global__ __launch_bounds__(256) void gemm_bf16(
    const unsigned short* __restrict__ A,   // [M][K] bf16, K contiguous
    const unsigned short* __restrict__ BT,  // [N][K] bf16, K contiguous
    const float* __restrict__ bias,         // [N]
    float* __restrict__ C,                  // [M][N] fp32
    int N, int K) {
  __shared__ unsigned short As[BM * BK];    // [128][64], unpadded (global_load_lds layout)
  __shared__ unsigned short Bs[BN * BK];
  int tid = threadIdx.x;
  int wave = tid >> 6, lane = tid & 63;
  int l15 = lane & 15, quad = lane >> 4;
  int m0 = blockIdx.y * BM, n0 = blockIdx.x * BN;
  int wm = (wave >> 1) * 64, wn = (wave & 1) * 64;
  int lrow = lane >> 3, lk = (lane & 7) * 8;
  floatx4 acc[4][4] = {};
  for (int kt = 0; kt < K; kt += BK) {
    __syncthreads();                        // LDS reuse guard
#pragma unroll
    for (int i = 0; i < 4; ++i) {
      int rb = wave * 32 + i * 8;           // wave-uniform row base (8 rows/instr)
      glds16(A  + (size_t)(m0 + rb + lrow) * K + kt + lk, As + rb * BK);
      glds16(BT + (size_t)(n0 + rb + lrow) * K + kt + lk, Bs + rb * BK);
    }
    __syncthreads();                        // drains vmcnt -> staging complete
#pragma unroll
    for (int ks = 0; ks < 2; ++ks) {
      short8 af[4], bv[4];
#pragma unroll
      for (int i = 0; i < 4; ++i)
        af[i] = *(const short8*)(As + (wm + i * 16 + l15) * BK + ks * 32 + quad * 8);
#pragma unroll
      for (int i = 0; i < 4; ++i)
        bv[i] = *(const short8*)(Bs + (wn + i * 16 + l15) * BK + ks * 32 + quad * 8);
#pragma unroll
      for (int mt = 0; mt < 4; ++mt)
#pragma unroll
        for (int nt = 0; nt < 4; ++nt)
          acc[mt][nt] = __builtin_amdgcn_mfma_f32_16x16x32_bf16(af[mt], bv[nt], acc[mt][nt], 0, 0, 0);
    }
  }
  // epilogue: C[m][n], row=quad*4+reg, col=lane&15 (m89-verified layout)
#pragma unroll
  for (int nt = 0; nt < 4; ++nt) {
    int gn = n0 + wn + nt * 16 + l15;
    float bvv = bias ? bias[gn] : 0.0f;
#pragma unroll
    for (int mt = 0; mt < 4; ++mt) {
      int gm = m0 + wm + mt * 16 + quad * 4;
#pragma unroll
      for (int r = 0; r < 4; ++r)
        C[(size_t)(gm + r) * N + gn] = acc[mt][nt][r] + bvv;
    }
  }
}

// ---------------- sequential scan: h_t = tanh(pre_t + h_{t-1} @ W_hh)
// 64 single-wave WGs, each owns 16 output cols; W_hh^T slice persistent in VGPRs as bf16 hi/lo.
// 3-term hi/lo MFMA gives effective-fp32 accuracy.
//
// R2 barrier redesign: no __threadfence (emitted buffer_wbl2/inv cache-maintenance per step),
// no single-line atomicAdd RMW contention (R1: 64 serialized RMWs ~= 13us/step).
// Instead: all h traffic uses agent-scope relaxed atomic ld/st (sc1, coherent at IC, no fences);
// arrival = one relaxed-release store to a per-(step,WG) flag; poll = lane i reads WG i's flag
// (one coalesced 256B load) + __all(). Zero RMWs, zero cache flushes.
#define SCAN_WGS 64

__device__ inline short8 ld_h16_agent(const unsigned long long* p) {
  unsigned long long a = __hip_atomic_load(p,     __ATOMIC_RELAXED, __HIP_MEMORY_SCOPE_AGENT);
  unsigned long long b = __hip_atomic_load(p + 1, __ATOMIC_RELAXED, __HIP_MEMORY_SCOPE_AGENT);
  union { unsigned long long u[2]; short8 s; } c;
  c.u[0] = a; c.u[1] = b;
  return c.s;
}

__global__ __launch_bounds__(64) void scan_kernel(
    const float* __restrict__ pre,            // [TB][HIDDIM], b_h already folded in
    const unsigned short* __restrict__ WThi,  // [m=1024][k=1024]  W_hh[k][m] hi
    const unsigned short* __restrict__ WTlo,
    unsigned short* __restrict__ h_hi,        // [TB][HIDDIM] hidden states (bf16 hi)
    unsigned short* __restrict__ h_lo,
    unsigned int* __restrict__ flags) {       // [T_STEPS][SCAN_WGS], pre-zeroed
  int lane = threadIdx.x;
  int l15 = lane & 15, quad = lane >> 4;
  int wg = blockIdx.x;
  int mslice = wg * 16;
  short8 Ahi[32], Alo[32];                    // A[m][k]: m=lane&15, k=quad*8+j
  {
    const unsigned short* wh = WThi + (size_t)(mslice + l15) * HIDDIM + quad * 8;
    const unsigned short* wl = WTlo + (size_t)(mslice + l15) * HIDDIM + quad * 8;
#pragma unroll
    for (int kt = 0; kt < 32; ++kt) {
      Ahi[kt] = *(const short8*)(wh + kt * 32);
      Alo[kt] = *(const short8*)(wl + kt * 32);
    }
  }
  for (int t = 0; t < T_STEPS; ++t) {
    // C[m][n]: this lane holds batch n=l15, cols mslice+quad*4+{0..3}
    size_t orow = ((size_t)t * BATCH + l15) * HIDDIM + mslice + quad * 4;
    float4 p = *(const float4*)(pre + orow);  // independent of barrier: issue early
    floatx4 acc = {0.f, 0.f, 0.f, 0.f};
    if (t > 0) {
      // wait for all 64 WGs to have published h_{t-1}
      const unsigned int* fl = flags + (size_t)(t - 1) * SCAN_WGS + lane;
      int guard = 0;
      while (true) {
        unsigned int v = __hip_atomic_load(fl, __ATOMIC_RELAXED, __HIP_MEMORY_SCOPE_AGENT);
        if (__all(v != 0)) break;
        __builtin_amdgcn_s_sleep(1);
        if (++guard > (1 << 22)) break;       // bounded failsafe; never trips normally
      }
      // B[k][n]: n=batch=lane&15, k=quad*8+j  ->  read h_{t-1}[n][k] (agent-scope, IC-coherent)
      const unsigned long long* bh =
          (const unsigned long long*)(h_hi + ((size_t)(t - 1) * BATCH + l15) * HIDDIM + quad * 8);
      const unsigned long long* bl =
          (const unsigned long long*)(h_lo + ((size_t)(t - 1) * BATCH + l15) * HIDDIM + quad * 8);
#pragma unroll
      for (int kt = 0; kt < 32; ++kt) {
        short8 Bh = ld_h16_agent(bh + kt * 8);   // 32 shorts = 8 ull per kt stride
        short8 Bl = ld_h16_agent(bl + kt * 8);
        acc = __builtin_amdgcn_mfma_f32_16x16x32_bf16(Ahi[kt], Bh, acc, 0, 0, 0);
        acc = __builtin_amdgcn_mfma_f32_16x16x32_bf16(Alo[kt], Bh, acc, 0, 0, 0);
        acc = __builtin_amdgcn_mfma_f32_16x16x32_bf16(Ahi[kt], Bl, acc, 0, 0, 0);
      }
    }
    ushort4 sh, sl;
    {
      float z, th; unsigned short hb;
      z = acc[0] + p.x; th = tanhf(z); hb = f2bfu(th); sh.x = hb; sl.x = f2bfu(th - bfu2f(hb));
      z = acc[1] + p.y; th = tanhf(z); hb = f2bfu(th); sh.y = hb; sl.y = f2bfu(th - bfu2f(hb));
      z = acc[2] + p.z; th = tanhf(z); hb = f2bfu(th); sh.z = hb; sl.z = f2bfu(th - bfu2f(hb));
      z = acc[3] + p.w; th = tanhf(z); hb = f2bfu(th); sh.w = hb; sl.w = f2bfu(th - bfu2f(hb));
    }
    // publish h_t with agent-scope stores (write-through to coherence point; no fence needed)
    union { ushort4 v; unsigned long long u; } ch, cl;
    ch.v = sh; cl.v = sl;
    __hip_atomic_store((unsigned long long*)(h_hi + orow), ch.u,
                       __ATOMIC_RELAXED, __HIP_MEMORY_SCOPE_AGENT);
    __hip_atomic_store((unsigned long long*)(h_lo + orow), cl.u,
                       __ATOMIC_RELAXED, __HIP_MEMORY_SCOPE_AGENT);
    // arrival flag: release orders it after the h stores (wave-level vmcnt(0) covers all lanes)
    __builtin_amdgcn_s_waitcnt(0);            // belt-and-braces: drain all outstanding stores
    if (lane == 0)
      __hip_atomic_store(flags + (size_t)t * SCAN_WGS + wg, 1u,
                         __ATOMIC_RELEASE, __HIP_MEMORY_SCOPE_AGENT);
  }
}

extern "C" void kernel_launch(void* const* d_in, const int* in_sizes, int n_in,
                              void* d_out, int out_size, void* d_ws, size_t ws_size,
                              hipStream_t stream) {
  const int*   X    = (const int*)d_in[0];
  const float* W_e  = (const float*)d_in[1];
  const float* W_xh = (const float*)d_in[2];
  const float* W_hh = (const float*)d_in[3];
  const float* b_h  = (const float*)d_in[4];
  const float* W_hq = (const float*)d_in[5];
  const float* b_q  = (const float*)d_in[6];
  float* out = (float*)d_out;

  char* w = (char*)d_ws;                                      // total used: ~113.9 MB
  unsigned short* WhqT   = (unsigned short*)(w + 0);          // 65,536,000  [32000][1024]
  unsigned short* WxhT   = (unsigned short*)(w + 65536000);   //  2,097,152  [1024][1024]
  unsigned short* WhhThi = (unsigned short*)(w + 67633152);   //  2,097,152
  unsigned short* WhhTlo = (unsigned short*)(w + 69730304);   //  2,097,152
  unsigned short* emb    = (unsigned short*)(w + 71827456);   //  8,388,608  [4096][1024]
  float*          pre    = (float*)        (w + 80216064);    // 16,777,216  [4096][1024]
  unsigned short* h_hi   = (unsigned short*)(w + 96993280);   //  8,388,608  [4096][1024]
  unsigned short* h_lo   = (unsigned short*)(w + 105381888);  //  8,388,608
  unsigned int*   flags  = (unsigned int*) (w + 113770496);   //  65,536  [256][64]

  hipMemsetAsync(flags, 0, T_STEPS * SCAN_WGS * sizeof(unsigned int), stream);
  transpose_cvt<<<dim3(VOCAB / 64, HIDDIM / 64), 256, 0, stream>>>(W_hq, WhqT, nullptr, HIDDIM, VOCAB);
  transpose_cvt<<<dim3(HIDDIM / 64, HIDDIM / 64), 256, 0, stream>>>(W_xh, WxhT, nullptr, HIDDIM, HIDDIM);
  transpose_cvt<<<dim3(HIDDIM / 64, HIDDIM / 64), 256, 0, stream>>>(W_hh, WhhThi, WhhTlo, HIDDIM, HIDDIM);
  gather_cvt<<<TB, 256, 0, stream>>>(X, W_e, emb);
  gemm_bf16<<<dim3(HIDDIM / BN, TB / BM), 256, 0, stream>>>(emb, WxhT, b_h, pre, HIDDIM, HIDDIM);
  scan_kernel<<<SCAN_WGS, 64, 0, stream>>>(pre, WhhThi, WhhTlo, h_hi, h_lo, flags);
  gemm_bf16<<<dim3(VOCAB / BN, TB / BM), 256, 0, stream>>>(h_hi, WhqT, b_q, out, VOCAB, HIDDIM);
}